// Round 3
// baseline (554.931 us; speedup 1.0000x reference)
//
#include <hip/hip_runtime.h>
#include <math.h>

// ---------------------------------------------------------------------------
// DeepBilateralNetCurves (HDRNet) forward, f32.
// Shapes (fixed by setup_inputs): B=2, lowres 3x256x256, fullres 3x1024x1024,
// grid 12 coeffs x 8 luma x 16x16, guide curve 16 pts.
// ---------------------------------------------------------------------------

// Generic direct 3x3 conv, pad=1, NCHW in / OIHW weights, optional bias+relu.
__global__ void conv3x3_k(const float* __restrict__ in, const float* __restrict__ wgt,
                          const float* __restrict__ bias, float* __restrict__ out,
                          int B, int Cin, int Hin, int Win,
                          int Cout, int Hout, int Wout,
                          int stride, int do_relu) {
    int total = B * Cout * Hout * Wout;
    int idx = blockIdx.x * blockDim.x + threadIdx.x;
    if (idx >= total) return;
    int wo = idx % Wout;
    int ho = (idx / Wout) % Hout;
    int co = (idx / (Wout * Hout)) % Cout;
    int b  = idx / (Wout * Hout * Cout);
    float acc = bias ? bias[co] : 0.0f;
    int hbase = ho * stride - 1;
    int wbase = wo * stride - 1;
    const float* wrow = wgt + (size_t)co * Cin * 9;
    const float* inb  = in + (size_t)b * Cin * Hin * Win;
    for (int ci = 0; ci < Cin; ++ci) {
        const float* ip = inb + (size_t)ci * Hin * Win;
        const float* wp = wrow + ci * 9;
#pragma unroll
        for (int ky = 0; ky < 3; ++ky) {
            int hi = hbase + ky;
            if (hi < 0 || hi >= Hin) continue;
#pragma unroll
            for (int kx = 0; kx < 3; ++kx) {
                int wi = wbase + kx;
                if (wi < 0 || wi >= Win) continue;
                acc += ip[hi * Win + wi] * wp[ky * 3 + kx];
            }
        }
    }
    if (do_relu) acc = fmaxf(acc, 0.0f);
    out[idx] = acc;
}

// Fully-connected: out[b,o] = bias[o] + sum_i in[b,i] * w[o,i]
__global__ void fc_k(const float* __restrict__ in, const float* __restrict__ wgt,
                     const float* __restrict__ bias, float* __restrict__ out,
                     int B, int IN, int OUT, int do_relu) {
    int idx = blockIdx.x * blockDim.x + threadIdx.x;
    if (idx >= B * OUT) return;
    int o = idx % OUT, b = idx / OUT;
    float acc = bias[o];
    const float* ip = in + (size_t)b * IN;
    const float* wp = wgt + (size_t)o * IN;
    for (int i = 0; i < IN; ++i) acc += ip[i] * wp[i];
    if (do_relu) acc = fmaxf(acc, 0.0f);
    out[idx] = acc;
}

// Fused: fusion = relu(fc2[b,i] + loc1[b,i,y,x]); co = 1x1 conv(pw,pb).
// Output re-laid out for slicing: sco[((b*16+y)*16+x)*96 + ch96],
// where ch96 = z*12 + c  (z = luma bin, c = coeff index 0..11).
__global__ void pred_k(const float* __restrict__ loc1, const float* __restrict__ fc2,
                       const float* __restrict__ pw, const float* __restrict__ pb,
                       float* __restrict__ sco, int B) {
    int total = B * 16 * 16 * 96;
    int idx = blockIdx.x * blockDim.x + threadIdx.x;
    if (idx >= total) return;
    int c = idx % 96;
    int x = (idx / 96) % 16;
    int y = (idx / (96 * 16)) % 16;
    int b = idx / (96 * 256);
    float acc = pb[c];
    const float* wp = pw + (size_t)c * 64;
    const float* fb = fc2 + (size_t)b * 64;
    const float* lb = loc1 + (size_t)b * 64 * 256 + y * 16 + x;
    for (int i = 0; i < 64; ++i) {
        float f = fb[i] + lb[(size_t)i * 256];
        acc += wp[i] * fmaxf(f, 0.0f);
    }
    sco[idx] = acc;
}

// Fused fullres pipeline: guidemap (ccm -> 16-pt piecewise-linear curve ->
// channel projection -> clamp[0,1]) -> trilinear grid slice -> affine apply.
__global__ void apply_k(const float* __restrict__ img, const float* __restrict__ sco,
                        const float* __restrict__ ccm_w, const float* __restrict__ ccm_b,
                        const float* __restrict__ shifts, const float* __restrict__ slopes,
                        const float* __restrict__ proj_w, const float* __restrict__ proj_b,
                        float* __restrict__ out, int B, int H, int W) {
    int total = B * H * W;
    int idx = blockIdx.x * blockDim.x + threadIdx.x;
    if (idx >= total) return;
    int w = idx % W;
    int h = (idx / W) % H;
    int b = idx / (W * H);
    size_t plane = (size_t)H * W;
    const float* ib = img + (size_t)b * 3 * plane + (size_t)h * W + w;
    float r  = ib[0];
    float g  = ib[plane];
    float bl = ib[2 * plane];

    // ---- guide ----
    float gd = proj_b[0];
#pragma unroll
    for (int c = 0; c < 3; ++c) {
        float v = ccm_b[c] + ccm_w[c * 3 + 0] * r + ccm_w[c * 3 + 1] * g + ccm_w[c * 3 + 2] * bl;
        float acc = 0.0f;
#pragma unroll
        for (int p = 0; p < 16; ++p)
            acc += slopes[c * 16 + p] * fmaxf(v - shifts[c * 16 + p], 0.0f);
        gd += proj_w[c] * acc;
    }
    gd = fminf(fmaxf(gd, 0.0f), 1.0f);

    // ---- trilinear slice (grid 16x16 spatial, 8 luma, 12 coeffs) ----
    float xs = ((float)w + 0.5f) * (16.0f / (float)W) - 0.5f;
    float ys = ((float)h + 0.5f) * (16.0f / (float)H) - 0.5f;
    float gz = gd * 8.0f - 0.5f;
    int fx = (int)floorf(xs);
    int fy = (int)floorf(ys);
    int fz = (int)floorf(gz);

    float coeff[12];
#pragma unroll
    for (int c = 0; c < 12; ++c) coeff[c] = 0.0f;

    const float* scob = sco + (size_t)b * 256 * 96;
#pragma unroll
    for (int dz = 0; dz < 2; ++dz) {
        int zi = min(max(fz + dz, 0), 7);
        float wz = fmaxf(1.0f - fabsf(gz - (float)(fz + dz)), 0.0f);
#pragma unroll
        for (int dy = 0; dy < 2; ++dy) {
            int yi = min(max(fy + dy, 0), 15);
            float wy = fmaxf(1.0f - fabsf(ys - (float)(fy + dy)), 0.0f);
#pragma unroll
            for (int dx = 0; dx < 2; ++dx) {
                int xi = min(max(fx + dx, 0), 15);
                float wx = fmaxf(1.0f - fabsf(xs - (float)(fx + dx)), 0.0f);
                float wt = wz * wy * wx;
                // 12 contiguous floats, 48B-aligned -> 3x float4 loads
                const float4* gp = (const float4*)(scob + ((size_t)(yi * 16 + xi) * 96 + zi * 12));
                float4 a0 = gp[0], a1 = gp[1], a2 = gp[2];
                coeff[0]  += wt * a0.x; coeff[1]  += wt * a0.y; coeff[2]  += wt * a0.z; coeff[3]  += wt * a0.w;
                coeff[4]  += wt * a1.x; coeff[5]  += wt * a1.y; coeff[6]  += wt * a1.z; coeff[7]  += wt * a1.w;
                coeff[8]  += wt * a2.x; coeff[9]  += wt * a2.y; coeff[10] += wt * a2.z; coeff[11] += wt * a2.w;
            }
        }
    }

    // ---- affine apply + clamp ----
    float* ob = out + (size_t)b * 3 * plane + (size_t)h * W + w;
#pragma unroll
    for (int o = 0; o < 3; ++o) {
        float v = coeff[o * 4 + 3] + coeff[o * 4 + 0] * r + coeff[o * 4 + 1] * g + coeff[o * 4 + 2] * bl;
        ob[o * plane] = fminf(fmaxf(v, 0.0f), 1.0f);
    }
}

static inline int cdiv(int a, int b) { return (a + b - 1) / b; }

extern "C" void kernel_launch(void* const* d_in, const int* in_sizes, int n_in,
                              void* d_out, int out_size, void* d_ws, size_t ws_size,
                              hipStream_t stream) {
    // inputs in setup_inputs() order
    const float* img_lo = (const float*)d_in[0];   // [B,3,256,256]
    const float* img_fr = (const float*)d_in[1];   // [B,3,1024,1024]
    const float* sw0 = (const float*)d_in[2];  const float* sb0 = (const float*)d_in[3];
    const float* sw1 = (const float*)d_in[4];  const float* sb1 = (const float*)d_in[5];
    const float* sw2 = (const float*)d_in[6];  const float* sb2 = (const float*)d_in[7];
    const float* sw3 = (const float*)d_in[8];  const float* sb3 = (const float*)d_in[9];
    const float* gw0 = (const float*)d_in[10]; const float* gb0 = (const float*)d_in[11];
    const float* gw1 = (const float*)d_in[12]; const float* gb1 = (const float*)d_in[13];
    const float* fw0 = (const float*)d_in[14]; const float* fb0 = (const float*)d_in[15];
    const float* fw1 = (const float*)d_in[16]; const float* fb1 = (const float*)d_in[17];
    const float* fw2 = (const float*)d_in[18]; const float* fb2 = (const float*)d_in[19];
    const float* lw0 = (const float*)d_in[20]; const float* lb0 = (const float*)d_in[21];
    const float* lw1 = (const float*)d_in[22];
    const float* pw  = (const float*)d_in[23]; const float* pb  = (const float*)d_in[24];
    const float* ccm_w  = (const float*)d_in[25]; const float* ccm_b = (const float*)d_in[26];
    const float* shifts = (const float*)d_in[27];
    const float* slopes = (const float*)d_in[28];
    const float* proj_w = (const float*)d_in[29];
    const float* proj_b = (const float*)d_in[30];
    float* out = (float*)d_out;

    const int B = in_sizes[0] / (3 * 256 * 256);   // = 2
    const int H = 1024, W = 1024;

    // workspace carve (floats)
    float* ws = (float*)d_ws;
    float* x0   = ws;                 // B*8*128*128
    float* x1   = x0 + (size_t)B * 8  * 128 * 128;   // B*16*64*64
    float* x2   = x1 + (size_t)B * 16 * 64 * 64;     // B*32*32*32
    float* x3   = x2 + (size_t)B * 32 * 32 * 32;     // B*64*16*16
    float* g0   = x3 + (size_t)B * 64 * 16 * 16;     // B*64*8*8
    float* g1   = g0 + (size_t)B * 64 * 8 * 8;       // B*64*4*4
    float* f0   = g1 + (size_t)B * 64 * 4 * 4;       // B*256
    float* f1   = f0 + (size_t)B * 256;              // B*128
    float* f2   = f1 + (size_t)B * 128;              // B*64
    float* loc0 = f2 + (size_t)B * 64;               // B*64*16*16
    float* loc1 = loc0 + (size_t)B * 64 * 16 * 16;   // B*64*16*16
    float* sco  = loc1 + (size_t)B * 64 * 16 * 16;   // B*256*96 (re-laid grid)

    const int T = 256;

    // splat chain
    conv3x3_k<<<cdiv(B * 8 * 128 * 128, T), T, 0, stream>>>(img_lo, sw0, sb0, x0, B, 3, 256, 256, 8, 128, 128, 2, 1);
    conv3x3_k<<<cdiv(B * 16 * 64 * 64, T), T, 0, stream>>>(x0, sw1, sb1, x1, B, 8, 128, 128, 16, 64, 64, 2, 1);
    conv3x3_k<<<cdiv(B * 32 * 32 * 32, T), T, 0, stream>>>(x1, sw2, sb2, x2, B, 16, 64, 64, 32, 32, 32, 2, 1);
    conv3x3_k<<<cdiv(B * 64 * 16 * 16, T), T, 0, stream>>>(x2, sw3, sb3, x3, B, 32, 32, 32, 64, 16, 16, 2, 1);
    // global path
    conv3x3_k<<<cdiv(B * 64 * 8 * 8, T), T, 0, stream>>>(x3, gw0, gb0, g0, B, 64, 16, 16, 64, 8, 8, 2, 1);
    conv3x3_k<<<cdiv(B * 64 * 4 * 4, T), T, 0, stream>>>(g0, gw1, gb1, g1, B, 64, 8, 8, 64, 4, 4, 2, 1);
    fc_k<<<cdiv(B * 256, T), T, 0, stream>>>(g1, fw0, fb0, f0, B, 1024, 256, 1);
    fc_k<<<cdiv(B * 128, T), T, 0, stream>>>(f0, fw1, fb1, f1, B, 256, 128, 1);
    fc_k<<<cdiv(B * 64, T), T, 0, stream>>>(f1, fw2, fb2, f2, B, 128, 64, 0);
    // local path
    conv3x3_k<<<cdiv(B * 64 * 16 * 16, T), T, 0, stream>>>(x3, lw0, lb0, loc0, B, 64, 16, 16, 64, 16, 16, 1, 1);
    conv3x3_k<<<cdiv(B * 64 * 16 * 16, T), T, 0, stream>>>(loc0, lw1, nullptr, loc1, B, 64, 16, 16, 64, 16, 16, 1, 0);
    // fusion + 1x1 pred -> slicing-layout grid
    pred_k<<<cdiv(B * 256 * 96, T), T, 0, stream>>>(loc1, f2, pw, pb, sco, B);
    // fullres: guide + slice + apply
    apply_k<<<cdiv(B * H * W, T), T, 0, stream>>>(img_fr, sco, ccm_w, ccm_b, shifts, slopes,
                                                  proj_w, proj_b, out, B, H, W);
}

// Round 4
// 166.812 us; speedup vs baseline: 3.3267x; 3.3267x over previous
//
#include <hip/hip_runtime.h>
#include <math.h>

// ---------------------------------------------------------------------------
// DeepBilateralNetCurves (HDRNet) forward, f32.
// B=2, lowres 3x256x256, fullres 3x1024x1024, grid 12x8x16x16, 16-pt curve.
//
// Round 3: kill the latency-bound serial reductions.
//  - fc_wave_k: one wave per output, lane-strided loads + shfl butterfly.
//  - conv_wave_k: one wave per output pixel (lane = input channel), for the
//    Cin=32/64 convs; inputs re-laid HWC for coalesced lane loads.
// ---------------------------------------------------------------------------

// Naive direct 3x3 conv, pad=1, CHW in / CHW out (conv0: 3->8, conv1: 8->16).
__global__ void conv3x3_k(const float* __restrict__ in, const float* __restrict__ wgt,
                          const float* __restrict__ bias, float* __restrict__ out,
                          int B, int Cin, int Hin, int Win,
                          int Cout, int Hout, int Wout,
                          int stride, int do_relu) {
    int total = B * Cout * Hout * Wout;
    int idx = blockIdx.x * blockDim.x + threadIdx.x;
    if (idx >= total) return;
    int wo = idx % Wout;
    int ho = (idx / Wout) % Hout;
    int co = (idx / (Wout * Hout)) % Cout;
    int b  = idx / (Wout * Hout * Cout);
    float acc = bias ? bias[co] : 0.0f;
    int hbase = ho * stride - 1;
    int wbase = wo * stride - 1;
    const float* wrow = wgt + (size_t)co * Cin * 9;
    const float* inb  = in + (size_t)b * Cin * Hin * Win;
    for (int ci = 0; ci < Cin; ++ci) {
        const float* ip = inb + (size_t)ci * Hin * Win;
        const float* wp = wrow + ci * 9;
#pragma unroll
        for (int ky = 0; ky < 3; ++ky) {
            int hi = hbase + ky;
            if (hi < 0 || hi >= Hin) continue;
#pragma unroll
            for (int kx = 0; kx < 3; ++kx) {
                int wi = wbase + kx;
                if (wi < 0 || wi >= Win) continue;
                acc += ip[hi * Win + wi] * wp[ky * 3 + kx];
            }
        }
    }
    if (do_relu) acc = fmaxf(acc, 0.0f);
    out[idx] = acc;
}

// Naive 3x3 conv, CHW in -> HWC out, co-fastest thread order (conv2: 16->32).
// idx = ((b*Hout+ho)*Wout+wo)*Cout+co  == HWC flat index directly.
__global__ void conv3x3_hwc_k(const float* __restrict__ in, const float* __restrict__ wgt,
                              const float* __restrict__ bias, float* __restrict__ out,
                              int B, int Cin, int Hin, int Win,
                              int Cout, int Hout, int Wout,
                              int stride, int do_relu) {
    int total = B * Cout * Hout * Wout;
    int idx = blockIdx.x * blockDim.x + threadIdx.x;
    if (idx >= total) return;
    int co = idx % Cout;
    int wo = (idx / Cout) % Wout;
    int ho = (idx / (Cout * Wout)) % Hout;
    int b  = idx / (Cout * Wout * Hout);
    float acc = bias ? bias[co] : 0.0f;
    int hbase = ho * stride - 1;
    int wbase = wo * stride - 1;
    const float* wrow = wgt + (size_t)co * Cin * 9;
    const float* inb  = in + (size_t)b * Cin * Hin * Win;
    for (int ci = 0; ci < Cin; ++ci) {
        const float* ip = inb + (size_t)ci * Hin * Win;
        const float* wp = wrow + ci * 9;
#pragma unroll
        for (int ky = 0; ky < 3; ++ky) {
            int hi = hbase + ky;
            if (hi < 0 || hi >= Hin) continue;
#pragma unroll
            for (int kx = 0; kx < 3; ++kx) {
                int wi = wbase + kx;
                if (wi < 0 || wi >= Win) continue;
                acc += ip[hi * Win + wi] * wp[ky * 3 + kx];
            }
        }
    }
    if (do_relu) acc = fmaxf(acc, 0.0f);
    out[idx] = acc;
}

// Wave-per-output 3x3 conv. Input HWC (channel-contiguous). lane = ci.
// Cin==64: one output/wave. Cin==32: two adjacent co per wave (half-waves).
// out_chw selects CHW (for the FC flatten) vs HWC output layout.
__global__ void conv_wave_k(const float* __restrict__ in, const float* __restrict__ wgt,
                            const float* __restrict__ bias, float* __restrict__ out,
                            int B, int Cin, int Hin, int Win,
                            int Cout, int Hout, int Wout,
                            int stride, int do_relu, int out_chw) {
    int tid  = blockIdx.x * blockDim.x + threadIdx.x;
    int wid  = tid >> 6;
    int lane = threadIdx.x & 63;
    int copw = (Cin == 64) ? 1 : 2;            // co computed per wave
    int cow  = Cout / copw;                    // co-groups
    int nw   = B * cow * Hout * Wout;
    if (wid >= nw) return;
    int cw = wid % cow;
    int wo = (wid / cow) % Wout;
    int ho = (wid / (cow * Wout)) % Hout;
    int b  = wid / (cow * Wout * Hout);
    int ci = lane & (Cin - 1);
    int co = cw * copw + ((copw == 2) ? (lane >> 5) : 0);

    int hbase = ho * stride - 1;
    int wbase = wo * stride - 1;
    const float* wp = wgt + ((size_t)co * Cin + ci) * 9;
    float acc = 0.0f;
#pragma unroll
    for (int ky = 0; ky < 3; ++ky) {
        int hi = hbase + ky;
        if (hi < 0 || hi >= Hin) continue;
#pragma unroll
        for (int kx = 0; kx < 3; ++kx) {
            int wi = wbase + kx;
            if (wi < 0 || wi >= Win) continue;
            acc += in[((size_t)(b * Hin + hi) * Win + wi) * Cin + ci] * wp[ky * 3 + kx];
        }
    }
    // butterfly reduce over the Cin lanes (stays within half-wave for Cin=32)
    for (int m = 1; m < Cin; m <<= 1) acc += __shfl_xor(acc, m);
    if ((lane & (Cin - 1)) == 0) {
        if (bias) acc += bias[co];
        if (do_relu) acc = fmaxf(acc, 0.0f);
        if (out_chw) out[((size_t)(b * Cout + co) * Hout + ho) * Wout + wo] = acc;
        else         out[((size_t)(b * Hout + ho) * Wout + wo) * Cout + co] = acc;
    }
}

// Wave-per-output fully-connected: out[b,o] = bias[o] + sum_i in[b,i]*w[o,i]
__global__ void fc_wave_k(const float* __restrict__ in, const float* __restrict__ wgt,
                          const float* __restrict__ bias, float* __restrict__ out,
                          int B, int IN, int OUT, int do_relu) {
    int tid  = blockIdx.x * blockDim.x + threadIdx.x;
    int wid  = tid >> 6;
    int lane = threadIdx.x & 63;
    if (wid >= B * OUT) return;
    int o = wid % OUT, b = wid / OUT;
    const float* ip = in + (size_t)b * IN;
    const float* wp = wgt + (size_t)o * IN;
    float acc = 0.0f;
    for (int j = lane; j < IN; j += 64) acc += ip[j] * wp[j];
    for (int m = 1; m < 64; m <<= 1) acc += __shfl_xor(acc, m);
    if (lane == 0) {
        acc += bias[o];
        if (do_relu) acc = fmaxf(acc, 0.0f);
        out[wid] = acc;  // wid = b*OUT + o
    }
}

// Fused: fusion = relu(fc2[b,i] + loc1_hwc[b,y,x,i]); co = 1x1 conv(pw,pb).
// Output re-laid for slicing: sco[((b*16+y)*16+x)*96 + z*12 + c].
__global__ void pred_k(const float* __restrict__ loc1, const float* __restrict__ fc2,
                       const float* __restrict__ pw, const float* __restrict__ pb,
                       float* __restrict__ sco, int B) {
    int total = B * 16 * 16 * 96;
    int idx = blockIdx.x * blockDim.x + threadIdx.x;
    if (idx >= total) return;
    int c = idx % 96;
    int x = (idx / 96) % 16;
    int y = (idx / (96 * 16)) % 16;
    int b = idx / (96 * 256);
    float acc = pb[c];
    const float* wp = pw + (size_t)c * 64;
    const float* fb = fc2 + (size_t)b * 64;
    const float* lb = loc1 + ((size_t)(b * 16 + y) * 16 + x) * 64;  // HWC: contiguous
    for (int i = 0; i < 64; ++i) {
        float f = fb[i] + lb[i];
        acc += wp[i] * fmaxf(f, 0.0f);
    }
    sco[idx] = acc;
}

// Fused fullres: guide (ccm -> 16-pt curve -> projection -> clamp) ->
// trilinear slice -> affine apply -> clamp.
__global__ void apply_k(const float* __restrict__ img, const float* __restrict__ sco,
                        const float* __restrict__ ccm_w, const float* __restrict__ ccm_b,
                        const float* __restrict__ shifts, const float* __restrict__ slopes,
                        const float* __restrict__ proj_w, const float* __restrict__ proj_b,
                        float* __restrict__ out, int B, int H, int W) {
    int total = B * H * W;
    int idx = blockIdx.x * blockDim.x + threadIdx.x;
    if (idx >= total) return;
    int w = idx % W;
    int h = (idx / W) % H;
    int b = idx / (W * H);
    size_t plane = (size_t)H * W;
    const float* ib = img + (size_t)b * 3 * plane + (size_t)h * W + w;
    float r  = ib[0];
    float g  = ib[plane];
    float bl = ib[2 * plane];

    float gd = proj_b[0];
#pragma unroll
    for (int c = 0; c < 3; ++c) {
        float v = ccm_b[c] + ccm_w[c * 3 + 0] * r + ccm_w[c * 3 + 1] * g + ccm_w[c * 3 + 2] * bl;
        float acc = 0.0f;
#pragma unroll
        for (int p = 0; p < 16; ++p)
            acc += slopes[c * 16 + p] * fmaxf(v - shifts[c * 16 + p], 0.0f);
        gd += proj_w[c] * acc;
    }
    gd = fminf(fmaxf(gd, 0.0f), 1.0f);

    float xs = ((float)w + 0.5f) * (16.0f / (float)W) - 0.5f;
    float ys = ((float)h + 0.5f) * (16.0f / (float)H) - 0.5f;
    float gz = gd * 8.0f - 0.5f;
    int fx = (int)floorf(xs);
    int fy = (int)floorf(ys);
    int fz = (int)floorf(gz);

    float coeff[12];
#pragma unroll
    for (int c = 0; c < 12; ++c) coeff[c] = 0.0f;

    const float* scob = sco + (size_t)b * 256 * 96;
#pragma unroll
    for (int dz = 0; dz < 2; ++dz) {
        int zi = min(max(fz + dz, 0), 7);
        float wz = fmaxf(1.0f - fabsf(gz - (float)(fz + dz)), 0.0f);
#pragma unroll
        for (int dy = 0; dy < 2; ++dy) {
            int yi = min(max(fy + dy, 0), 15);
            float wy = fmaxf(1.0f - fabsf(ys - (float)(fy + dy)), 0.0f);
#pragma unroll
            for (int dx = 0; dx < 2; ++dx) {
                int xi = min(max(fx + dx, 0), 15);
                float wx = fmaxf(1.0f - fabsf(xs - (float)(fx + dx)), 0.0f);
                float wt = wz * wy * wx;
                const float4* gp = (const float4*)(scob + ((size_t)(yi * 16 + xi) * 96 + zi * 12));
                float4 a0 = gp[0], a1 = gp[1], a2 = gp[2];
                coeff[0]  += wt * a0.x; coeff[1]  += wt * a0.y; coeff[2]  += wt * a0.z; coeff[3]  += wt * a0.w;
                coeff[4]  += wt * a1.x; coeff[5]  += wt * a1.y; coeff[6]  += wt * a1.z; coeff[7]  += wt * a1.w;
                coeff[8]  += wt * a2.x; coeff[9]  += wt * a2.y; coeff[10] += wt * a2.z; coeff[11] += wt * a2.w;
            }
        }
    }

    float* ob = out + (size_t)b * 3 * plane + (size_t)h * W + w;
#pragma unroll
    for (int o = 0; o < 3; ++o) {
        float v = coeff[o * 4 + 3] + coeff[o * 4 + 0] * r + coeff[o * 4 + 1] * g + coeff[o * 4 + 2] * bl;
        ob[o * plane] = fminf(fmaxf(v, 0.0f), 1.0f);
    }
}

static inline int cdiv(int a, int b) { return (a + b - 1) / b; }

extern "C" void kernel_launch(void* const* d_in, const int* in_sizes, int n_in,
                              void* d_out, int out_size, void* d_ws, size_t ws_size,
                              hipStream_t stream) {
    const float* img_lo = (const float*)d_in[0];   // [B,3,256,256]
    const float* img_fr = (const float*)d_in[1];   // [B,3,1024,1024]
    const float* sw0 = (const float*)d_in[2];  const float* sb0 = (const float*)d_in[3];
    const float* sw1 = (const float*)d_in[4];  const float* sb1 = (const float*)d_in[5];
    const float* sw2 = (const float*)d_in[6];  const float* sb2 = (const float*)d_in[7];
    const float* sw3 = (const float*)d_in[8];  const float* sb3 = (const float*)d_in[9];
    const float* gw0 = (const float*)d_in[10]; const float* gb0 = (const float*)d_in[11];
    const float* gw1 = (const float*)d_in[12]; const float* gb1 = (const float*)d_in[13];
    const float* fw0 = (const float*)d_in[14]; const float* fb0 = (const float*)d_in[15];
    const float* fw1 = (const float*)d_in[16]; const float* fb1 = (const float*)d_in[17];
    const float* fw2 = (const float*)d_in[18]; const float* fb2 = (const float*)d_in[19];
    const float* lw0 = (const float*)d_in[20]; const float* lb0 = (const float*)d_in[21];
    const float* lw1 = (const float*)d_in[22];
    const float* pw  = (const float*)d_in[23]; const float* pb  = (const float*)d_in[24];
    const float* ccm_w  = (const float*)d_in[25]; const float* ccm_b = (const float*)d_in[26];
    const float* shifts = (const float*)d_in[27];
    const float* slopes = (const float*)d_in[28];
    const float* proj_w = (const float*)d_in[29];
    const float* proj_b = (const float*)d_in[30];
    float* out = (float*)d_out;

    const int B = in_sizes[0] / (3 * 256 * 256);   // = 2
    const int H = 1024, W = 1024;

    // workspace carve (floats)
    float* ws = (float*)d_ws;
    float* x0   = ws;                                // B*8*128*128   CHW
    float* x1   = x0 + (size_t)B * 8  * 128 * 128;   // B*16*64*64    CHW
    float* x2   = x1 + (size_t)B * 16 * 64 * 64;     // B*32*32*32    HWC
    float* x3   = x2 + (size_t)B * 32 * 32 * 32;     // B*16*16*64    HWC
    float* g0   = x3 + (size_t)B * 64 * 16 * 16;     // B*8*8*64      HWC
    float* g1   = g0 + (size_t)B * 64 * 8 * 8;       // B*64*4*4      CHW (FC flatten order)
    float* f0   = g1 + (size_t)B * 64 * 4 * 4;       // B*256
    float* f1   = f0 + (size_t)B * 256;              // B*128
    float* f2   = f1 + (size_t)B * 128;              // B*64
    float* loc0 = f2 + (size_t)B * 64;               // B*16*16*64    HWC
    float* loc1 = loc0 + (size_t)B * 64 * 16 * 16;   // B*16*16*64    HWC
    float* sco  = loc1 + (size_t)B * 64 * 16 * 16;   // B*256*96 slicing layout

    const int T = 256;

    // splat chain
    conv3x3_k<<<cdiv(B * 8 * 128 * 128, T), T, 0, stream>>>(img_lo, sw0, sb0, x0, B, 3, 256, 256, 8, 128, 128, 2, 1);
    conv3x3_k<<<cdiv(B * 16 * 64 * 64, T), T, 0, stream>>>(x0, sw1, sb1, x1, B, 8, 128, 128, 16, 64, 64, 2, 1);
    conv3x3_hwc_k<<<cdiv(B * 32 * 32 * 32, T), T, 0, stream>>>(x1, sw2, sb2, x2, B, 16, 64, 64, 32, 32, 32, 2, 1);
    // conv3: Cin=32 wave-conv, HWC in -> HWC out
    conv_wave_k<<<cdiv(B * (64 / 2) * 16 * 16 * 64, T), T, 0, stream>>>(x2, sw3, sb3, x3, B, 32, 32, 32, 64, 16, 16, 2, 1, 0);
    // global path (Cin=64 wave-convs)
    conv_wave_k<<<cdiv(B * 64 * 8 * 8 * 64, T), T, 0, stream>>>(x3, gw0, gb0, g0, B, 64, 16, 16, 64, 8, 8, 2, 1, 0);
    conv_wave_k<<<cdiv(B * 64 * 4 * 4 * 64, T), T, 0, stream>>>(g0, gw1, gb1, g1, B, 64, 8, 8, 64, 4, 4, 2, 1, 1);
    fc_wave_k<<<cdiv(B * 256 * 64, T), T, 0, stream>>>(g1, fw0, fb0, f0, B, 1024, 256, 1);
    fc_wave_k<<<cdiv(B * 128 * 64, T), T, 0, stream>>>(f0, fw1, fb1, f1, B, 256, 128, 1);
    fc_wave_k<<<cdiv(B * 64 * 64, T), T, 0, stream>>>(f1, fw2, fb2, f2, B, 128, 64, 0);
    // local path (Cin=64 wave-convs, HWC in/out)
    conv_wave_k<<<cdiv(B * 64 * 16 * 16 * 64, T), T, 0, stream>>>(x3, lw0, lb0, loc0, B, 64, 16, 16, 64, 16, 16, 1, 1, 0);
    conv_wave_k<<<cdiv(B * 64 * 16 * 16 * 64, T), T, 0, stream>>>(loc0, lw1, nullptr, loc1, B, 64, 16, 16, 64, 16, 16, 1, 0, 0);
    // fusion + 1x1 pred -> slicing-layout grid
    pred_k<<<cdiv(B * 256 * 96, T), T, 0, stream>>>(loc1, f2, pw, pb, sco, B);
    // fullres: guide + slice + apply
    apply_k<<<cdiv(B * H * W, T), T, 0, stream>>>(img_fr, sco, ccm_w, ccm_b, shifts, slopes,
                                                  proj_w, proj_b, out, B, H, W);
}